// Round 1
// baseline (427.183 us; speedup 1.0000x reference)
//
#include <hip/hip_runtime.h>
#include <hip/hip_bf16.h>

#define HIDDEN 1024
#define INTER 2048
#define NE 8
#define GS 128
#define TOKENS 4096
#define MAXROWS 9216  // 8192 routed rows + 8*128 padding capacity
#define MAXTILES 72   // 128-row tiles (gemm2)
#define MAXT256 40    // 256-row tiles (gemm1); sum ceil(m_e/2) <= 40

typedef __bf16 bf16x8 __attribute__((ext_vector_type(8)));
typedef float f32x4 __attribute__((ext_vector_type(4)));

// ---- ws layout v3 (bytes) ----
#define OFF_TOPKI 0u               // int[4096][2]
#define OFF_TOPKW 32768u           // float[4096][2]
#define OFF_CTRL  65536u           // int[32]: [0..7]=hist [8..15]=scatter ctr [16..23]=offsets [24]=padded total [25]=ntiles128 [26]=ntiles256
#define OFF_TOK   66048u           // int[MAXROWS]
#define OFF_SLOT  102912u          // int[TOKENS*2]
#define OFF_TILE  135680u          // int[MAXTILES] tile -> (e<<20 | row0)
#define OFF_T256  136192u          // int[MAXT256]  tile -> (e<<20 | row0)
#define OFF_V256  136448u          // int[MAXT256]  valid rows in 256-tile
#define OFF_XB    139776u          // bf16[TOKENS+1][HIDDEN]  (row TOKENS = zeros)
#define OFF_A     8530432u         // bf16[MAXROWS][INTER]
#define OFF_W1D   46279168u        // bf16[NE][4096][HIDDEN] INTERLEAVED gate/up per 16 rows (dead after gemm1)
#define OFF_W2D   113388032u       // bf16[NE][1024][INTER]  -> 146942464 total
#define OFF_Y0    OFF_W1D          // bf16[MAXROWS][HIDDEN]  (aliases dead w1d)
#define OFF_Y1    (OFF_W1D + 18874368u)

__device__ __forceinline__ unsigned short f2bf(float f) {
  union { float f; unsigned int u; } v; v.f = f;
  unsigned int r = (v.u + 0x7FFFu + ((v.u >> 16) & 1u)) >> 16;
  return (unsigned short)r;
}
__device__ __forceinline__ float bf2f(unsigned int u) {
  union { unsigned int u; float f; } v; v.u = u << 16;
  return v.f;
}
__device__ __forceinline__ unsigned int pack2(unsigned short lo, unsigned short hi) {
  return (unsigned int)lo | ((unsigned int)hi << 16);
}

// async global->LDS, 16B per lane. LDS dest is wave-uniform base + lane*16.
typedef const __attribute__((address_space(1))) unsigned int GAS;
typedef __attribute__((address_space(3))) unsigned int LAS;
__device__ __forceinline__ void gload16(const unsigned short* g, unsigned short* l) {
  __builtin_amdgcn_global_load_lds((GAS*)g, (LAS*)l, 16, 0, 0);
}

// ---- prep: router(+hist) | deq1(interleaved) | deq2 | x->bf16 | zero-row ---
// block ranges: [0,1024) router, [1024,17408) deq1, [17408,25600) deq2,
//               [25600,29696) xconv, 29696 zero-row.  No LDS -> full occupancy.
__global__ __launch_bounds__(256) void k_prep(const float* __restrict__ x,
    const float* __restrict__ rw, int* __restrict__ topki, float* __restrict__ topkw,
    const int* __restrict__ w1, const float* __restrict__ w1s,
    unsigned short* __restrict__ w1d,
    const int* __restrict__ w2, const float* __restrict__ w2s,
    unsigned short* __restrict__ w2d, unsigned short* __restrict__ xb,
    int* __restrict__ ctrl) {
  int bid = blockIdx.x, tid = threadIdx.x;
  if (bid == 29696) {
    uint2 z; z.x = 0u; z.y = 0u;
    *reinterpret_cast<uint2*>(xb + (size_t)TOKENS * HIDDEN + tid * 4) = z;
    return;
  }
  if (bid >= 25600) {
    size_t idx = (size_t)(bid - 25600) * 1024 + tid * 4;
    float4 v = *reinterpret_cast<const float4*>(x + idx);
    uint2 o;
    o.x = pack2(f2bf(v.x), f2bf(v.y));
    o.y = pack2(f2bf(v.z), f2bf(v.w));
    *reinterpret_cast<uint2*>(xb + idx) = o;
    return;
  }
  if (bid >= 17408) {
    int gid = (bid - 17408) * 256 + tid;
    int i4 = gid * 4;
    int r = i4 >> 10;
    int i = i4 & 1023;
    float s = w2s[r * 16 + (i >> 6)];
    int4 p = *reinterpret_cast<const int4*>(w2 + (size_t)i4);
    int pv[4] = { p.x, p.y, p.z, p.w };
    uint4 o; unsigned int ov[4];
#pragma unroll
    for (int j = 0; j < 4; j++) {
      float lo = (float)((pv[j] & 15) - 8) * s;
      float hi = (float)(((pv[j] >> 4) & 15) - 8) * s;
      ov[j] = pack2(f2bf(lo), f2bf(hi));
    }
    o.x = ov[0]; o.y = ov[1]; o.z = ov[2]; o.w = ov[3];
    *reinterpret_cast<uint4*>(w2d + ((size_t)r << 11) + 2 * i) = o;
    return;
  }
  if (bid >= 1024) {
    // deq1: write w1d with gate/up interleaved at 16-row granularity:
    // semantic col j, type tp(0=gate,1=up) -> il_row = (j>>4)*32 + tp*16 + (j&15)
    int gid = (bid - 1024) * 256 + tid;
    int i4 = gid * 4;
    int r = i4 >> 9;           // global w1 row: e*4096 + rr
    int i = i4 & 511;
    float s = w1s[r * 8 + (i >> 6)];
    int4 p = *reinterpret_cast<const int4*>(w1 + (size_t)i4);
    int pv[4] = { p.x, p.y, p.z, p.w };
    uint4 o; unsigned int ov[4];
#pragma unroll
    for (int j = 0; j < 4; j++) {
      float lo = (float)((pv[j] & 15) - 8) * s;
      float hi = (float)(((pv[j] >> 4) & 15) - 8) * s;
      ov[j] = pack2(f2bf(lo), f2bf(hi));
    }
    o.x = ov[0]; o.y = ov[1]; o.z = ov[2]; o.w = ov[3];
    int e = r >> 12, rr = r & 4095;
    int tp = rr >> 11, jj = rr & 2047;
    int il = ((jj >> 4) << 5) + (tp << 4) + (jj & 15);
    size_t orow = ((size_t)e << 12) + il;
    *reinterpret_cast<uint4*>(w1d + (orow << 10) + 2 * i) = o;
    return;
  }
  // ---- router ----
  int wave = tid >> 6, lane = tid & 63;
  int t = bid * 4 + wave;
  float acc[NE];
#pragma unroll
  for (int e = 0; e < NE; e++) acc[e] = 0.f;
  const float* xr = x + (size_t)t * HIDDEN;
  for (int i = lane; i < HIDDEN; i += 64) {
    float xv = xr[i];
#pragma unroll
    for (int e = 0; e < NE; e++) acc[e] += xv * rw[e * HIDDEN + i];
  }
#pragma unroll
  for (int e = 0; e < NE; e++) {
    float v = acc[e];
    for (int off = 32; off > 0; off >>= 1) v += __shfl_down(v, off, 64);
    acc[e] = v;
  }
  if (lane == 0) {
    int b0 = 0; float s0 = acc[0];
#pragma unroll
    for (int e = 1; e < NE; e++) if (acc[e] > s0) { s0 = acc[e]; b0 = e; }
    int b1 = -1; float s1 = -3.0e38f;
#pragma unroll
    for (int e = 0; e < NE; e++) if (e != b0 && acc[e] > s1) { s1 = acc[e]; b1 = e; }
    float w0 = 1.f / (1.f + __expf(s1 - s0));
    topki[t * 2] = b0; topki[t * 2 + 1] = b1;
    topkw[t * 2] = w0; topkw[t * 2 + 1] = 1.f - w0;
    atomicAdd(&ctrl[b0], 1);
    atomicAdd(&ctrl[b1], 1);
  }
}

// ------- route2 (1 block): offsets + both tilemaps + pad fill ---------------
// hist already in ctrl[0..7] (from k_prep atomics). Scatter moved to k_scatter.
__global__ __launch_bounds__(256) void k_route2(int* __restrict__ ctrl,
    int* __restrict__ tok, int* __restrict__ tilemap,
    int* __restrict__ tile256, int* __restrict__ valid256) {
  __shared__ int h[NE], off[NE];
  int tid = threadIdx.x;
  if (tid < NE) h[tid] = ctrl[tid];
  __syncthreads();
  if (tid == 0) {
    int run = 0, t = 0, t2 = 0;
    for (int e = 0; e < NE; e++) {
      int c = h[e];
      ctrl[16 + e] = run; off[e] = run;
      ctrl[8 + e] = run;                 // scatter counter init
      int pc = (c + 127) & ~127;
      int m = pc >> 7;
      for (int mt = 0; mt < m; mt++) tilemap[t++] = (e << 20) | (run + mt * 128);
      // 256-row tiles: overlap last tile back into the 128-padded region.
      int n2 = (m + 1) >> 1;
      for (int i = 0; i < n2; i++) {
        int st = i * 256;
        if (st + 256 > pc) st = (pc >= 256) ? (pc - 256) : 0;
        tile256[t2] = (e << 20) | (run + st);
        int v = pc - st; valid256[t2] = (v < 256) ? v : 256;
        t2++;
      }
      run += pc;
    }
    ctrl[24] = run; ctrl[25] = t; ctrl[26] = t2;
  }
  __syncthreads();
#pragma unroll
  for (int e = 0; e < NE; e++) {
    int c = h[e], pc = (c + 127) & ~127;
    for (int i = c + tid; i < pc; i += 256) tok[off[e] + i] = -1;
  }
}

// ------- scatter (32 blocks): two-level aggregation, low atomic contention --
__global__ __launch_bounds__(256) void k_scatter(const int* __restrict__ topki,
    int* __restrict__ ctrl, int* __restrict__ tok, int* __restrict__ slots) {
  __shared__ int lh[NE], lbase[NE];
  int tid = threadIdx.x;
  int i = blockIdx.x * 256 + tid;
  if (tid < NE) lh[tid] = 0;
  __syncthreads();
  int e = topki[i];
  int lp = atomicAdd(&lh[e], 1);
  __syncthreads();
  if (tid < NE) lbase[tid] = lh[tid] ? atomicAdd(&ctrl[8 + tid], lh[tid]) : 0;
  __syncthreads();
  int p = lbase[e] + lp;
  tok[p] = i >> 1;
  slots[i] = p;
}

// --------------- GEMM1: 8-phase 256x256 BK=64, 8 waves, fused silu ---------
// a = silu(gate)*up from gather(xb) @ w1d_il^T.  w1d_il interleaves gate/up per
// 16 rows so fragment pairs (2p, 2p+1) are gate/up of the SAME output col.
// LDS: 2 dbuf x 2 half x [128 rows x 64 cols] x {A,B} = 128 KB.
// Half-tile layout: [row' = kk*128 + r][32 cols], row stride 64B; col-block
// swizzle c' = c ^ ((r>>1)&3)  (same measured-0-conflict pattern as before),
// applied via pre-swizzled global source (gload_lds writes linearly).
// Staging schedule per k-tile (phases q0..q3 = C-quadrants (mh,nh)):
//   q0: read A[mh=0](8) + B[nh=0](4); stage (kt+1).A1 -> buf^1
//   q1: read B[nh=1](4);              stage nothing
//   q2: read A[mh=1](8);              stage (kt+2).B0 -> buf
//   q3: (reads none);                 stage (kt+2).B1,(kt+2).A0 -> buf
//       s_waitcnt vmcnt(6)  (= 3 half-tiles of kt+2 stay in flight)
// B-halves are register-cached across the tile, A-halves across 2 phases, so
// every LDS slot's last read precedes its overwrite by >=1 barrier.
#define STAGE_A(buf, h, kt) do { \
    const unsigned short* _g = ((h) ? pA1 : pA0) + (kt) * 64; \
    unsigned short* _l = (unsigned short*)sA + (buf) * 16384 + (h) * 8192 + tid * 8; \
    gload16(_g, _l); gload16(_g + 32, _l + 4096); } while (0)
#define STAGE_B(buf, h, kt) do { \
    const unsigned short* _g = ((h) ? pB1 : pB0) + (kt) * 64; \
    unsigned short* _l = (unsigned short*)sB + (buf) * 16384 + (h) * 8192 + tid * 8; \
    gload16(_g, _l); gload16(_g + 32, _l + 4096); } while (0)

__global__ __launch_bounds__(512, 2) void k_gemm1(
    const unsigned short* __restrict__ xb, const unsigned short* __restrict__ w1d,
    const int* __restrict__ ctrl, const int* __restrict__ tile256,
    const int* __restrict__ valid256, const int* __restrict__ tok,
    unsigned short* __restrict__ a_out) {
  __shared__ unsigned short sA[32768];   // 64 KB
  __shared__ unsigned short sB[32768];   // 64 KB
  int bid = blockIdx.x, tid = threadIdx.x;
  int nt = bid & 15, tile = bid >> 4;
  if (tile >= ctrl[26]) return;
  int tm = tile256[tile];
  int e = tm >> 20, row0 = tm & 0xFFFFF;
  int vrows = valid256[tile];
  int total = ctrl[24];
  int n0 = nt * 256;
  int wave = tid >> 6, lane = tid & 63, ln = lane & 15, quad = lane >> 4;
  int wm = wave >> 2, wn = wave & 3;

  // staging mapping: thread t covers half-row sr, LDS col-block t&3; source is
  // pre-swizzled so linear LDS write lands the swizzled layout.
  int sr = tid >> 2;
  int gsw = ((tid & 3) ^ ((sr >> 1) & 3)) * 8;
  int gr0 = row0 + sr, gr1 = row0 + 128 + sr;
  int t0 = (gr0 < total) ? tok[gr0] : -1;
  int t1 = (gr1 < total) ? tok[gr1] : -1;
  const unsigned short* pA0 = xb + (size_t)(t0 < 0 ? TOKENS : t0) * HIDDEN + gsw;
  const unsigned short* pA1 = xb + (size_t)(t1 < 0 ? TOKENS : t1) * HIDDEN + gsw;
  const unsigned short* pB0 = w1d + (((size_t)e * 4096 + n0 + sr) << 10) + gsw;
  const unsigned short* pB1 = pB0 + ((size_t)128 << 10);

  // prologue: t0 fully, then t1.{B0,B1,A0}; vmcnt(6) drains exactly t0.
  STAGE_A(0, 0, 0); STAGE_B(0, 0, 0); STAGE_B(0, 1, 0); STAGE_A(0, 1, 0);
  STAGE_B(1, 0, 1); STAGE_B(1, 1, 1); STAGE_A(1, 0, 1);
  asm volatile("s_waitcnt vmcnt(6)" ::: "memory");
  __builtin_amdgcn_s_barrier();

  int cb = ln * 32 + (quad ^ ((ln >> 1) & 3)) * 8;   // swizzled read offset
  int bb = (wn & 1) * 2048 + cb;
  f32x4 acc[8][4] = {};
  bf16x8 af[4][2], b0r[2][2], b1r[2][2];

  for (int kt = 0; kt < 16; kt++) {
    int buf = kt & 1;
    const unsigned short* A = sA + (buf * 2 + wm) * 8192;
    const unsigned short* B = sB + (buf * 2 + (wn >> 1)) * 8192;
    int kn1 = (kt + 1 < 16) ? kt + 1 : 15;   // clamped redundant prefetch keeps
    int kn2 = (kt + 2 < 16) ? kt + 2 : 15;   // per-wave vmcnt counts uniform
    // ---------------- phase q0: quadrant (mh=0, nh=0) ----------------
#pragma unroll
    for (int mi = 0; mi < 4; mi++)
#pragma unroll
      for (int kk = 0; kk < 2; kk++)
        af[mi][kk] = *reinterpret_cast<const bf16x8*>(A + kk * 4096 + mi * 512 + cb);
#pragma unroll
    for (int ni = 0; ni < 2; ni++)
#pragma unroll
      for (int kk = 0; kk < 2; kk++)
        b0r[ni][kk] = *reinterpret_cast<const bf16x8*>(B + kk * 4096 + ni * 512 + bb);
    STAGE_A(buf ^ 1, 1, kn1);
    asm volatile("s_waitcnt lgkmcnt(8)" ::: "memory");
    __builtin_amdgcn_s_barrier();
    asm volatile("s_waitcnt lgkmcnt(0)" ::: "memory");
    __builtin_amdgcn_s_setprio(1);
#pragma unroll
    for (int mi = 0; mi < 4; mi++)
#pragma unroll
      for (int ni = 0; ni < 2; ni++)
#pragma unroll
        for (int kk = 0; kk < 2; kk++)
          acc[mi][ni] = __builtin_amdgcn_mfma_f32_16x16x32_bf16(af[mi][kk], b0r[ni][kk], acc[mi][ni], 0, 0, 0);
    __builtin_amdgcn_s_setprio(0);
    __builtin_amdgcn_s_barrier();
    // ---------------- phase q1: quadrant (mh=0, nh=1) ----------------
#pragma unroll
    for (int ni = 0; ni < 2; ni++)
#pragma unroll
      for (int kk = 0; kk < 2; kk++)
        b1r[ni][kk] = *reinterpret_cast<const bf16x8*>(B + kk * 4096 + (2 + ni) * 512 + bb);
    __builtin_amdgcn_s_barrier();
    asm volatile("s_waitcnt lgkmcnt(0)" ::: "memory");
    __builtin_amdgcn_s_setprio(1);
#pragma unroll
    for (int mi = 0; mi < 4; mi++)
#pragma unroll
      for (int ni = 0; ni < 2; ni++)
#pragma unroll
        for (int kk = 0; kk < 2; kk++)
          acc[mi][2 + ni] = __builtin_amdgcn_mfma_f32_16x16x32_bf16(af[mi][kk], b1r[ni][kk], acc[mi][2 + ni], 0, 0, 0);
    __builtin_amdgcn_s_setprio(0);
    __builtin_amdgcn_s_barrier();
    // ---------------- phase q2: quadrant (mh=1, nh=0) ----------------
#pragma unroll
    for (int mi = 0; mi < 4; mi++)
#pragma unroll
      for (int kk = 0; kk < 2; kk++)
        af[mi][kk] = *reinterpret_cast<const bf16x8*>(A + kk * 4096 + (4 + mi) * 512 + cb);
    STAGE_B(buf, 0, kn2);
    __builtin_amdgcn_s_barrier();
    asm volatile("s_waitcnt lgkmcnt(0)" ::: "memory");
    __builtin_amdgcn_s_setprio(1);
#pragma unroll
    for (int mi = 0; mi < 4; mi++)
#pragma unroll
      for (int ni = 0; ni < 2; ni++)
#pragma unroll
        for (int kk = 0; kk < 2; kk++)
          acc[4 + mi][ni] = __builtin_amdgcn_mfma_f32_16x16x32_bf16(af[mi][kk], b0r[ni][kk], acc[4 + mi][ni], 0, 0, 0);
    __builtin_amdgcn_s_setprio(0);
    __builtin_amdgcn_s_barrier();
    // ---------------- phase q3: quadrant (mh=1, nh=1) ----------------
    STAGE_B(buf, 1, kn2);
    STAGE_A(buf, 0, kn2);
    __builtin_amdgcn_s_barrier();
    __builtin_amdgcn_s_setprio(1);
#pragma unroll
    for (int mi = 0; mi < 4; mi++)
#pragma unroll
      for (int ni = 0; ni < 2; ni++)
#pragma unroll
        for (int kk = 0; kk < 2; kk++)
          acc[4 + mi][2 + ni] = __builtin_amdgcn_mfma_f32_16x16x32_bf16(af[mi][kk], b1r[ni][kk], acc[4 + mi][2 + ni], 0, 0, 0);
    __builtin_amdgcn_s_setprio(0);
    asm volatile("s_waitcnt vmcnt(6)" ::: "memory");
    __builtin_amdgcn_s_barrier();
  }
  asm volatile("s_waitcnt vmcnt(0)" ::: "memory");

  // epilogue: fragment pair (2p, 2p+1) = (gate, up) of the same semantic col.
  int jb = nt * 128 + wn * 32;
  int rb = row0 + wm * 128;
#pragma unroll
  for (int mf = 0; mf < 8; mf++)
#pragma unroll
    for (int p = 0; p < 2; p++)
#pragma unroll
      for (int r = 0; r < 4; r++) {
        float g = acc[mf][2 * p][r], u = acc[mf][2 * p + 1][r];
        float act = (g / (1.f + __expf(-g))) * u;
        int lr = wm * 128 + mf * 16 + quad * 4 + r;
        if (lr < vrows)
          a_out[(size_t)(row0 + lr) * INTER + jb + p * 16 + ln] = f2bf(act);
      }
}

// ------- GEMM2 split-K x2: y[kp][slot] = a[:,kp*1024:+1024] @ w2^T ---------
// 128x128 tile, BK=32. bid: kp = bid&1, nt = (bid>>1)&7, tile = bid>>4.
__global__ __launch_bounds__(256) void k_gemm2(
    const unsigned short* __restrict__ a_in, const unsigned short* __restrict__ w2d,
    const int* __restrict__ ctrl, const int* __restrict__ tilemap,
    unsigned short* __restrict__ y) {
  __shared__ unsigned short sA[128 * 32];   // 8 KB
  __shared__ unsigned short sB[128 * 32];   // 8 KB
  int bid = blockIdx.x, tid = threadIdx.x;
  int kp = bid & 1, nt = (bid >> 1) & 7, tile = bid >> 4;
  if (tile >= ctrl[25]) return;
  int tm = tilemap[tile];
  int e = tm >> 20, row0 = tm & 0xFFFFF;
  int n0 = nt * 128;
  int wave = tid >> 6, lane = tid & 63;
  int ln = lane & 15, quad = lane >> 4;
  int wr = (wave & 1) * 64, wc = (wave >> 1) * 64;

  int srow = tid >> 2, scblk = tid & 3;
  int scol = (scblk ^ ((srow >> 1) & 3)) * 8;
  int kbase = kp * (INTER / 2);
  const unsigned short* gA0 = a_in + (size_t)(row0 + srow) * INTER + kbase + scol;
  const unsigned short* gA1 = gA0 + (size_t)64 * INTER;
  const unsigned short* gB0 = w2d + ((size_t)e * 1024 + n0 + srow) * INTER + kbase + scol;
  const unsigned short* gB1 = gB0 + (size_t)64 * INTER;
  unsigned short* lA0 = sA + tid * 8;
  unsigned short* lA1 = sA + 64 * 32 + tid * 8;
  unsigned short* lB0 = sB + tid * 8;
  unsigned short* lB1 = sB + 64 * 32 + tid * 8;

  f32x4 acc[4][4] = {};
  for (int k0 = 0; k0 < INTER / 2; k0 += 32) {
    __syncthreads();
    gload16(gA0 + k0, lA0);
    gload16(gA1 + k0, lA1);
    gload16(gB0 + k0, lB0);
    gload16(gB1 + k0, lB1);
    __syncthreads();
    bf16x8 af[4], bf_[4];
#pragma unroll
    for (int m = 0; m < 4; m++) {
      int ar = wr + m * 16 + ln;
      af[m] = *reinterpret_cast<const bf16x8*>(&sA[ar * 32 + (quad ^ ((ar >> 1) & 3)) * 8]);
    }
#pragma unroll
    for (int n = 0; n < 4; n++) {
      int br = wc + n * 16 + ln;
      bf_[n] = *reinterpret_cast<const bf16x8*>(&sB[br * 32 + (quad ^ ((br >> 1) & 3)) * 8]);
    }
#pragma unroll
    for (int m = 0; m < 4; m++)
#pragma unroll
      for (int n = 0; n < 4; n++)
        acc[m][n] = __builtin_amdgcn_mfma_f32_16x16x32_bf16(af[m], bf_[n], acc[m][n], 0, 0, 0);
  }
  unsigned short* yk = y + (size_t)kp * MAXROWS * HIDDEN;
#pragma unroll
  for (int m = 0; m < 4; m++)
#pragma unroll
    for (int n = 0; n < 4; n++) {
      int col = n0 + wc + n * 16 + ln;
#pragma unroll
      for (int r = 0; r < 4; r++) {
        int row = row0 + wr + m * 16 + quad * 4 + r;
        yk[(size_t)row * HIDDEN + col] = f2bf(acc[m][n][r]);
      }
    }
}

// ------- combine: out[t] = g0*(y0[s0]+y1[s0]) + g1*(y0[s1]+y1[s1]) ---------
__global__ __launch_bounds__(256) void k_combine(const unsigned short* __restrict__ y,
    const int* __restrict__ slots, const float* __restrict__ topkw,
    float* __restrict__ out) {
  int t = blockIdx.x;
  int c = threadIdx.x * 4;
  int s0 = slots[t * 2], s1 = slots[t * 2 + 1];
  float g0 = topkw[t * 2], g1 = topkw[t * 2 + 1];
  const unsigned short* y1 = y + (size_t)MAXROWS * HIDDEN;
  uint2 a0 = *reinterpret_cast<const uint2*>(y  + (size_t)s0 * HIDDEN + c);
  uint2 a1 = *reinterpret_cast<const uint2*>(y1 + (size_t)s0 * HIDDEN + c);
  uint2 b0 = *reinterpret_cast<const uint2*>(y  + (size_t)s1 * HIDDEN + c);
  uint2 b1 = *reinterpret_cast<const uint2*>(y1 + (size_t)s1 * HIDDEN + c);
  float4 o;
  o.x = g0 * (bf2f(a0.x & 0xffffu) + bf2f(a1.x & 0xffffu))
      + g1 * (bf2f(b0.x & 0xffffu) + bf2f(b1.x & 0xffffu));
  o.y = g0 * (bf2f(a0.x >> 16) + bf2f(a1.x >> 16))
      + g1 * (bf2f(b0.x >> 16) + bf2f(b1.x >> 16));
  o.z = g0 * (bf2f(a0.y & 0xffffu) + bf2f(a1.y & 0xffffu))
      + g1 * (bf2f(b0.y & 0xffffu) + bf2f(b1.y & 0xffffu));
  o.w = g0 * (bf2f(a0.y >> 16) + bf2f(a1.y >> 16))
      + g1 * (bf2f(b0.y >> 16) + bf2f(b1.y >> 16));
  *reinterpret_cast<float4*>(out + (size_t)t * HIDDEN + c) = o;
}

extern "C" void kernel_launch(void* const* d_in, const int* in_sizes, int n_in,
                              void* d_out, int out_size, void* d_ws, size_t ws_size,
                              hipStream_t stream) {
  const float* x   = (const float*)d_in[0];
  const float* rw  = (const float*)d_in[1];
  const int*   w1  = (const int*)d_in[2];
  const float* w1s = (const float*)d_in[3];
  const int*   w2  = (const int*)d_in[4];
  const float* w2s = (const float*)d_in[5];
  float* out = (float*)d_out;
  char* ws = (char*)d_ws;

  int*   topki = (int*)(ws + OFF_TOPKI);
  float* topkw = (float*)(ws + OFF_TOPKW);
  int*   ctrl  = (int*)(ws + OFF_CTRL);
  int*   tok   = (int*)(ws + OFF_TOK);
  int*   slots = (int*)(ws + OFF_SLOT);
  int*   tilemap = (int*)(ws + OFF_TILE);
  int*   tile256 = (int*)(ws + OFF_T256);
  int*   valid256 = (int*)(ws + OFF_V256);
  unsigned short* xb  = (unsigned short*)(ws + OFF_XB);
  unsigned short* a   = (unsigned short*)(ws + OFF_A);
  unsigned short* w1d = (unsigned short*)(ws + OFF_W1D);
  unsigned short* w2d = (unsigned short*)(ws + OFF_W2D);
  unsigned short* y   = (unsigned short*)(ws + OFF_Y0);  // y1 = y + MAXROWS*HIDDEN

  hipMemsetAsync(ws + OFF_CTRL, 0, 128, stream);
  k_prep<<<29697, 256, 0, stream>>>(x, rw, topki, topkw, w1, w1s, w1d, w2, w2s, w2d, xb, ctrl);
  k_route2<<<1, 256, 0, stream>>>(ctrl, tok, tilemap, tile256, valid256);
  k_scatter<<<32, 256, 0, stream>>>(topki, ctrl, tok, slots);
  k_gemm1<<<16 * MAXT256, 512, 0, stream>>>(xb, w1d, ctrl, tile256, valid256, tok, a);
  k_gemm2<<<16 * MAXTILES, 256, 0, stream>>>(a, w2d, ctrl, tilemap, y);
  k_combine<<<TOKENS, 256, 0, stream>>>(y, slots, topkw, out);
}

// Round 2
// 353.107 us; speedup vs baseline: 1.2098x; 1.2098x over previous
//
#include <hip/hip_runtime.h>
#include <hip/hip_bf16.h>

#define HIDDEN 1024
#define INTER 2048
#define NE 8
#define GS 128
#define TOKENS 4096
#define MAXROWS 9216  // 8192 routed rows + 8*128 padding capacity
#define MAXTILES 72   // 128-row tiles (gemm2)
#define MAXT256 40    // 256-row tiles (gemm1); sum ceil(m_e/2) <= 40

typedef __bf16 bf16x8 __attribute__((ext_vector_type(8)));
typedef float f32x4 __attribute__((ext_vector_type(4)));

// ---- ws layout v3 (bytes) ----
#define OFF_TOPKI 0u               // int[4096][2]
#define OFF_TOPKW 32768u           // float[4096][2]
#define OFF_CTRL  65536u           // int[32]: [0..7]=counts [16..23]=offsets [24]=padded total [25]=ntiles128 [26]=ntiles256
#define OFF_TOK   66048u           // int[MAXROWS]
#define OFF_SLOT  102912u          // int[TOKENS*2]
#define OFF_TILE  135680u          // int[MAXTILES] tile -> (e<<20 | row0)
#define OFF_T256  136192u          // int[MAXT256]  tile -> (e<<20 | row0)
#define OFF_V256  136448u          // int[MAXT256]  valid rows in 256-tile
#define OFF_XB    139776u          // bf16[TOKENS+1][HIDDEN]  (row TOKENS = zeros)
#define OFF_A     8530432u         // bf16[MAXROWS][INTER]
#define OFF_W1D   46279168u        // bf16[NE][4096][HIDDEN] LINEAR rows (dead after gemm1)
#define OFF_W2D   113388032u       // bf16[NE][1024][INTER]  -> 146942464 total
#define OFF_Y0    OFF_W1D          // bf16[MAXROWS][HIDDEN]  (aliases dead w1d)
#define OFF_Y1    (OFF_W1D + 18874368u)

__device__ __forceinline__ unsigned short f2bf(float f) {
  union { float f; unsigned int u; } v; v.f = f;
  unsigned int r = (v.u + 0x7FFFu + ((v.u >> 16) & 1u)) >> 16;
  return (unsigned short)r;
}
__device__ __forceinline__ float bf2f(unsigned int u) {
  union { unsigned int u; float f; } v; v.u = u << 16;
  return v.f;
}
__device__ __forceinline__ unsigned int pack2(unsigned short lo, unsigned short hi) {
  return (unsigned int)lo | ((unsigned int)hi << 16);
}

// async global->LDS, 16B per lane. LDS dest is wave-uniform base + lane*16.
typedef const __attribute__((address_space(1))) unsigned int GAS;
typedef __attribute__((address_space(3))) unsigned int LAS;
__device__ __forceinline__ void gload16(const unsigned short* g, unsigned short* l) {
  __builtin_amdgcn_global_load_lds((GAS*)g, (LAS*)l, 16, 0, 0);
}

// ---- prep: router | deq1 | deq2 | x->bf16 conv | zero-row ------------------
// EXACT round-0 version (measured good): linear w1d writes, no atomics.
__global__ __launch_bounds__(256) void k_prep(const float* __restrict__ x,
    const float* __restrict__ rw, int* __restrict__ topki, float* __restrict__ topkw,
    const int* __restrict__ w1, const float* __restrict__ w1s,
    unsigned short* __restrict__ w1d,
    const int* __restrict__ w2, const float* __restrict__ w2s,
    unsigned short* __restrict__ w2d, unsigned short* __restrict__ xb) {
  int bid = blockIdx.x, tid = threadIdx.x;
  if (bid == 29696) {
    uint2 z; z.x = 0u; z.y = 0u;
    *reinterpret_cast<uint2*>(xb + (size_t)TOKENS * HIDDEN + tid * 4) = z;
    return;
  }
  if (bid >= 25600) {
    size_t idx = (size_t)(bid - 25600) * 1024 + tid * 4;
    float4 v = *reinterpret_cast<const float4*>(x + idx);
    uint2 o;
    o.x = pack2(f2bf(v.x), f2bf(v.y));
    o.y = pack2(f2bf(v.z), f2bf(v.w));
    *reinterpret_cast<uint2*>(xb + idx) = o;
    return;
  }
  if (bid >= 17408) {
    int gid = (bid - 17408) * 256 + tid;
    int i4 = gid * 4;
    int r = i4 >> 10;
    int i = i4 & 1023;
    float s = w2s[r * 16 + (i >> 6)];
    int4 p = *reinterpret_cast<const int4*>(w2 + (size_t)i4);
    int pv[4] = { p.x, p.y, p.z, p.w };
    uint4 o; unsigned int ov[4];
#pragma unroll
    for (int j = 0; j < 4; j++) {
      float lo = (float)((pv[j] & 15) - 8) * s;
      float hi = (float)(((pv[j] >> 4) & 15) - 8) * s;
      ov[j] = pack2(f2bf(lo), f2bf(hi));
    }
    o.x = ov[0]; o.y = ov[1]; o.z = ov[2]; o.w = ov[3];
    *reinterpret_cast<uint4*>(w2d + ((size_t)r << 11) + 2 * i) = o;
    return;
  }
  if (bid >= 1024) {
    int gid = (bid - 1024) * 256 + tid;
    int i4 = gid * 4;
    int r = i4 >> 9;
    int i = i4 & 511;
    float s = w1s[r * 8 + (i >> 6)];
    int4 p = *reinterpret_cast<const int4*>(w1 + (size_t)i4);
    int pv[4] = { p.x, p.y, p.z, p.w };
    uint4 o; unsigned int ov[4];
#pragma unroll
    for (int j = 0; j < 4; j++) {
      float lo = (float)((pv[j] & 15) - 8) * s;
      float hi = (float)(((pv[j] >> 4) & 15) - 8) * s;
      ov[j] = pack2(f2bf(lo), f2bf(hi));
    }
    o.x = ov[0]; o.y = ov[1]; o.z = ov[2]; o.w = ov[3];
    *reinterpret_cast<uint4*>(w1d + ((size_t)r << 10) + 2 * i) = o;
    return;
  }
  // ---- router ----
  int wave = tid >> 6, lane = tid & 63;
  int t = bid * 4 + wave;
  float acc[NE];
#pragma unroll
  for (int e = 0; e < NE; e++) acc[e] = 0.f;
  const float* xr = x + (size_t)t * HIDDEN;
  for (int i = lane; i < HIDDEN; i += 64) {
    float xv = xr[i];
#pragma unroll
    for (int e = 0; e < NE; e++) acc[e] += xv * rw[e * HIDDEN + i];
  }
#pragma unroll
  for (int e = 0; e < NE; e++) {
    float v = acc[e];
    for (int off = 32; off > 0; off >>= 1) v += __shfl_down(v, off, 64);
    acc[e] = v;
  }
  if (lane == 0) {
    int b0 = 0; float s0 = acc[0];
#pragma unroll
    for (int e = 1; e < NE; e++) if (acc[e] > s0) { s0 = acc[e]; b0 = e; }
    int b1 = -1; float s1 = -3.0e38f;
#pragma unroll
    for (int e = 0; e < NE; e++) if (e != b0 && acc[e] > s1) { s1 = acc[e]; b1 = e; }
    float w0 = 1.f / (1.f + __expf(s1 - s0));
    topki[t * 2] = b0; topki[t * 2 + 1] = b1;
    topkw[t * 2] = w0; topkw[t * 2 + 1] = 1.f - w0;
  }
}

// ------- route2 (1 block): hist + offsets + tilemaps + pad fill + scatter ---
// Round-0 version + 256-row tilemap generation for the 8-phase gemm1.
__global__ __launch_bounds__(256) void k_route2(const int* __restrict__ topki,
    int* __restrict__ ctrl, int* __restrict__ tok, int* __restrict__ slots,
    int* __restrict__ tilemap, int* __restrict__ tile256, int* __restrict__ valid256) {
  __shared__ int h[NE], off[NE], cnt[NE];
  int tid = threadIdx.x;
  if (tid < NE) h[tid] = 0;
  __syncthreads();
  for (int i = tid; i < TOKENS * 2; i += 256) atomicAdd(&h[topki[i]], 1);
  __syncthreads();
  if (tid == 0) {
    int run = 0, t = 0, t2 = 0;
    for (int e = 0; e < NE; e++) {
      int c = h[e];
      ctrl[e] = c; ctrl[16 + e] = run; off[e] = run;
      int pc = (c + 127) & ~127;
      int m = pc >> 7;
      for (int mt = 0; mt < m; mt++) tilemap[t++] = (e << 20) | (run + mt * 128);
      // 256-row tiles: overlap last tile back into the 128-padded region.
      int n2 = (m + 1) >> 1;
      for (int i2 = 0; i2 < n2; i2++) {
        int st = i2 * 256;
        if (st + 256 > pc) st = (pc >= 256) ? (pc - 256) : 0;
        tile256[t2] = (e << 20) | (run + st);
        int v = pc - st; valid256[t2] = (v < 256) ? v : 256;
        t2++;
      }
      run += pc;
    }
    ctrl[24] = run; ctrl[25] = t; ctrl[26] = t2;
  }
  __syncthreads();
#pragma unroll
  for (int e = 0; e < NE; e++) {
    int c = h[e], pc = (c + 127) & ~127;
    for (int i = c + tid; i < pc; i += 256) tok[off[e] + i] = -1;
  }
  if (tid < NE) cnt[tid] = off[tid];
  __syncthreads();
  for (int i = tid; i < TOKENS * 2; i += 256) {
    int e = topki[i];
    int p = atomicAdd(&cnt[e], 1);
    tok[p] = i >> 1;
    slots[i] = p;
  }
}

// --------------- GEMM1: 8-phase 256x256 BK=64, 8 waves, fused silu ---------
// a = silu(gate)*up from gather(xb) @ perm(w1d)^T.  w1d stays LINEAR in memory
// (gate rows [0,2048), up rows [2048,4096) per expert); the gate/up 16-row
// interleave is applied on the STAGING SOURCE pointer (global_load_lds source
// is per-lane), so fragment pairs (2p, 2p+1) are gate/up of the SAME out col:
//   LDS il-row q -> src row ((q>>4)&1)*2048 + (q>>5)*16 + (q&15)
// LDS: 2 dbuf x 2 half x [128 rows x 64 cols] x {A,B} = 128 KB, 1 block/CU.
// Col-block swizzle c' = c ^ ((r>>1)&3) via pre-swizzled source; counted
// vmcnt(6) keeps 3 half-tiles in flight across barriers (never drains to 0).
#define STAGE_A(buf, h, kt) do { \
    const unsigned short* _g = ((h) ? pA1 : pA0) + (kt) * 64; \
    unsigned short* _l = (unsigned short*)sA + (buf) * 16384 + (h) * 8192 + tid * 8; \
    gload16(_g, _l); gload16(_g + 32, _l + 4096); } while (0)
#define STAGE_B(buf, h, kt) do { \
    const unsigned short* _g = ((h) ? pB1 : pB0) + (kt) * 64; \
    unsigned short* _l = (unsigned short*)sB + (buf) * 16384 + (h) * 8192 + tid * 8; \
    gload16(_g, _l); gload16(_g + 32, _l + 4096); } while (0)

__global__ __launch_bounds__(512, 2) void k_gemm1(
    const unsigned short* __restrict__ xb, const unsigned short* __restrict__ w1d,
    const int* __restrict__ ctrl, const int* __restrict__ tile256,
    const int* __restrict__ valid256, const int* __restrict__ tok,
    unsigned short* __restrict__ a_out) {
  __shared__ unsigned short sA[32768];   // 64 KB
  __shared__ unsigned short sB[32768];   // 64 KB
  int bid = blockIdx.x, tid = threadIdx.x;
  int nt = bid & 15, tile = bid >> 4;
  if (tile >= ctrl[26]) return;
  int tm = tile256[tile];
  int e = tm >> 20, row0 = tm & 0xFFFFF;
  int vrows = valid256[tile];
  int total = ctrl[24];
  int n0 = nt * 256;
  int wave = tid >> 6, lane = tid & 63, ln = lane & 15, quad = lane >> 4;
  int wm = wave >> 2, wn = wave & 3;

  // staging mapping: thread t covers half-row sr, LDS col-block t&3; source is
  // pre-swizzled so the linear LDS write lands the swizzled layout.
  int sr = tid >> 2;
  int gsw = ((tid & 3) ^ ((sr >> 1) & 3)) * 8;
  int gr0 = row0 + sr, gr1 = row0 + 128 + sr;
  int t0 = (gr0 < total) ? tok[gr0] : -1;
  int t1 = (gr1 < total) ? tok[gr1] : -1;
  const unsigned short* pA0 = xb + (size_t)(t0 < 0 ? TOKENS : t0) * HIDDEN + gsw;
  const unsigned short* pA1 = xb + (size_t)(t1 < 0 ? TOKENS : t1) * HIDDEN + gsw;
  // B source rows: un-interleave from the linear w1d layout.
  int qb0 = n0 + sr, qb1 = qb0 + 128;
  int sb0 = ((qb0 >> 4) & 1) * 2048 + ((qb0 >> 5) << 4) + (qb0 & 15);
  int sb1 = ((qb1 >> 4) & 1) * 2048 + ((qb1 >> 5) << 4) + (qb1 & 15);
  const unsigned short* pB0 = w1d + (((size_t)e * 4096 + sb0) << 10) + gsw;
  const unsigned short* pB1 = w1d + (((size_t)e * 4096 + sb1) << 10) + gsw;

  // prologue: t0 fully, then t1.{B0,B1,A0}; vmcnt(6) drains exactly t0.
  STAGE_A(0, 0, 0); STAGE_B(0, 0, 0); STAGE_B(0, 1, 0); STAGE_A(0, 1, 0);
  STAGE_B(1, 0, 1); STAGE_B(1, 1, 1); STAGE_A(1, 0, 1);
  asm volatile("s_waitcnt vmcnt(6)" ::: "memory");
  __builtin_amdgcn_s_barrier();

  int cb = ln * 32 + (quad ^ ((ln >> 1) & 3)) * 8;   // swizzled read offset
  int bb = (wn & 1) * 2048 + cb;
  f32x4 acc[8][4] = {};
  bf16x8 af[4][2], b0r[2][2], b1r[2][2];

  for (int kt = 0; kt < 16; kt++) {
    int buf = kt & 1;
    const unsigned short* A = sA + (buf * 2 + wm) * 8192;
    const unsigned short* B = sB + (buf * 2 + (wn >> 1)) * 8192;
    int kn1 = (kt + 1 < 16) ? kt + 1 : 15;   // clamped redundant prefetch keeps
    int kn2 = (kt + 2 < 16) ? kt + 2 : 15;   // per-wave vmcnt counts uniform
    // ---------------- phase q0: quadrant (mh=0, nh=0) ----------------
#pragma unroll
    for (int mi = 0; mi < 4; mi++)
#pragma unroll
      for (int kk = 0; kk < 2; kk++)
        af[mi][kk] = *reinterpret_cast<const bf16x8*>(A + kk * 4096 + mi * 512 + cb);
#pragma unroll
    for (int ni = 0; ni < 2; ni++)
#pragma unroll
      for (int kk = 0; kk < 2; kk++)
        b0r[ni][kk] = *reinterpret_cast<const bf16x8*>(B + kk * 4096 + ni * 512 + bb);
    STAGE_A(buf ^ 1, 1, kn1);
    asm volatile("s_waitcnt lgkmcnt(8)" ::: "memory");
    __builtin_amdgcn_s_barrier();
    asm volatile("s_waitcnt lgkmcnt(0)" ::: "memory");
    __builtin_amdgcn_s_setprio(1);
#pragma unroll
    for (int mi = 0; mi < 4; mi++)
#pragma unroll
      for (int ni = 0; ni < 2; ni++)
#pragma unroll
        for (int kk = 0; kk < 2; kk++)
          acc[mi][ni] = __builtin_amdgcn_mfma_f32_16x16x32_bf16(af[mi][kk], b0r[ni][kk], acc[mi][ni], 0, 0, 0);
    __builtin_amdgcn_s_setprio(0);
    __builtin_amdgcn_s_barrier();
    // ---------------- phase q1: quadrant (mh=0, nh=1) ----------------
#pragma unroll
    for (int ni = 0; ni < 2; ni++)
#pragma unroll
      for (int kk = 0; kk < 2; kk++)
        b1r[ni][kk] = *reinterpret_cast<const bf16x8*>(B + kk * 4096 + (2 + ni) * 512 + bb);
    __builtin_amdgcn_s_barrier();
    asm volatile("s_waitcnt lgkmcnt(0)" ::: "memory");
    __builtin_amdgcn_s_setprio(1);
#pragma unroll
    for (int mi = 0; mi < 4; mi++)
#pragma unroll
      for (int ni = 0; ni < 2; ni++)
#pragma unroll
        for (int kk = 0; kk < 2; kk++)
          acc[mi][2 + ni] = __builtin_amdgcn_mfma_f32_16x16x32_bf16(af[mi][kk], b1r[ni][kk], acc[mi][2 + ni], 0, 0, 0);
    __builtin_amdgcn_s_setprio(0);
    __builtin_amdgcn_s_barrier();
    // ---------------- phase q2: quadrant (mh=1, nh=0) ----------------
#pragma unroll
    for (int mi = 0; mi < 4; mi++)
#pragma unroll
      for (int kk = 0; kk < 2; kk++)
        af[mi][kk] = *reinterpret_cast<const bf16x8*>(A + kk * 4096 + (4 + mi) * 512 + cb);
    STAGE_B(buf, 0, kn2);
    __builtin_amdgcn_s_barrier();
    asm volatile("s_waitcnt lgkmcnt(0)" ::: "memory");
    __builtin_amdgcn_s_setprio(1);
#pragma unroll
    for (int mi = 0; mi < 4; mi++)
#pragma unroll
      for (int ni = 0; ni < 2; ni++)
#pragma unroll
        for (int kk = 0; kk < 2; kk++)
          acc[4 + mi][ni] = __builtin_amdgcn_mfma_f32_16x16x32_bf16(af[mi][kk], b0r[ni][kk], acc[4 + mi][ni], 0, 0, 0);
    __builtin_amdgcn_s_setprio(0);
    __builtin_amdgcn_s_barrier();
    // ---------------- phase q3: quadrant (mh=1, nh=1) ----------------
    STAGE_B(buf, 1, kn2);
    STAGE_A(buf, 0, kn2);
    __builtin_amdgcn_s_barrier();
    __builtin_amdgcn_s_setprio(1);
#pragma unroll
    for (int mi = 0; mi < 4; mi++)
#pragma unroll
      for (int ni = 0; ni < 2; ni++)
#pragma unroll
        for (int kk = 0; kk < 2; kk++)
          acc[4 + mi][2 + ni] = __builtin_amdgcn_mfma_f32_16x16x32_bf16(af[mi][kk], b1r[ni][kk], acc[4 + mi][2 + ni], 0, 0, 0);
    __builtin_amdgcn_s_setprio(0);
    asm volatile("s_waitcnt vmcnt(6)" ::: "memory");
    __builtin_amdgcn_s_barrier();
  }
  asm volatile("s_waitcnt vmcnt(0)" ::: "memory");

  // epilogue: fragment pair (2p, 2p+1) = (gate, up) of the same semantic col.
  int jb = nt * 128 + wn * 32;
#pragma unroll
  for (int mf = 0; mf < 8; mf++)
#pragma unroll
    for (int p = 0; p < 2; p++)
#pragma unroll
      for (int r = 0; r < 4; r++) {
        float g = acc[mf][2 * p][r], u = acc[mf][2 * p + 1][r];
        float act = (g / (1.f + __expf(-g))) * u;
        int lr = wm * 128 + mf * 16 + quad * 4 + r;
        if (lr < vrows)
          a_out[(size_t)(row0 + lr) * INTER + jb + p * 16 + ln] = f2bf(act);
      }
}

// ------- GEMM2 split-K x2: y[kp][slot] = a[:,kp*1024:+1024] @ w2^T ---------
// 128x128 tile, BK=32. bid: kp = bid&1, nt = (bid>>1)&7, tile = bid>>4.
__global__ __launch_bounds__(256) void k_gemm2(
    const unsigned short* __restrict__ a_in, const unsigned short* __restrict__ w2d,
    const int* __restrict__ ctrl, const int* __restrict__ tilemap,
    unsigned short* __restrict__ y) {
  __shared__ unsigned short sA[128 * 32];   // 8 KB
  __shared__ unsigned short sB[128 * 32];   // 8 KB
  int bid = blockIdx.x, tid = threadIdx.x;
  int kp = bid & 1, nt = (bid >> 1) & 7, tile = bid >> 4;
  if (tile >= ctrl[25]) return;
  int tm = tilemap[tile];
  int e = tm >> 20, row0 = tm & 0xFFFFF;
  int n0 = nt * 128;
  int wave = tid >> 6, lane = tid & 63;
  int ln = lane & 15, quad = lane >> 4;
  int wr = (wave & 1) * 64, wc = (wave >> 1) * 64;

  int srow = tid >> 2, scblk = tid & 3;
  int scol = (scblk ^ ((srow >> 1) & 3)) * 8;
  int kbase = kp * (INTER / 2);
  const unsigned short* gA0 = a_in + (size_t)(row0 + srow) * INTER + kbase + scol;
  const unsigned short* gA1 = gA0 + (size_t)64 * INTER;
  const unsigned short* gB0 = w2d + ((size_t)e * 1024 + n0 + srow) * INTER + kbase + scol;
  const unsigned short* gB1 = gB0 + (size_t)64 * INTER;
  unsigned short* lA0 = sA + tid * 8;
  unsigned short* lA1 = sA + 64 * 32 + tid * 8;
  unsigned short* lB0 = sB + tid * 8;
  unsigned short* lB1 = sB + 64 * 32 + tid * 8;

  f32x4 acc[4][4] = {};
  for (int k0 = 0; k0 < INTER / 2; k0 += 32) {
    __syncthreads();
    gload16(gA0 + k0, lA0);
    gload16(gA1 + k0, lA1);
    gload16(gB0 + k0, lB0);
    gload16(gB1 + k0, lB1);
    __syncthreads();
    bf16x8 af[4], bf_[4];
#pragma unroll
    for (int m = 0; m < 4; m++) {
      int ar = wr + m * 16 + ln;
      af[m] = *reinterpret_cast<const bf16x8*>(&sA[ar * 32 + (quad ^ ((ar >> 1) & 3)) * 8]);
    }
#pragma unroll
    for (int n = 0; n < 4; n++) {
      int br = wc + n * 16 + ln;
      bf_[n] = *reinterpret_cast<const bf16x8*>(&sB[br * 32 + (quad ^ ((br >> 1) & 3)) * 8]);
    }
#pragma unroll
    for (int m = 0; m < 4; m++)
#pragma unroll
      for (int n = 0; n < 4; n++)
        acc[m][n] = __builtin_amdgcn_mfma_f32_16x16x32_bf16(af[m], bf_[n], acc[m][n], 0, 0, 0);
  }
  unsigned short* yk = y + (size_t)kp * MAXROWS * HIDDEN;
#pragma unroll
  for (int m = 0; m < 4; m++)
#pragma unroll
    for (int n = 0; n < 4; n++) {
      int col = n0 + wc + n * 16 + ln;
#pragma unroll
      for (int r = 0; r < 4; r++) {
        int row = row0 + wr + m * 16 + quad * 4 + r;
        yk[(size_t)row * HIDDEN + col] = f2bf(acc[m][n][r]);
      }
    }
}

// ------- combine: out[t] = g0*(y0[s0]+y1[s0]) + g1*(y0[s1]+y1[s1]) ---------
__global__ __launch_bounds__(256) void k_combine(const unsigned short* __restrict__ y,
    const int* __restrict__ slots, const float* __restrict__ topkw,
    float* __restrict__ out) {
  int t = blockIdx.x;
  int c = threadIdx.x * 4;
  int s0 = slots[t * 2], s1 = slots[t * 2 + 1];
  float g0 = topkw[t * 2], g1 = topkw[t * 2 + 1];
  const unsigned short* y1 = y + (size_t)MAXROWS * HIDDEN;
  uint2 a0 = *reinterpret_cast<const uint2*>(y  + (size_t)s0 * HIDDEN + c);
  uint2 a1 = *reinterpret_cast<const uint2*>(y1 + (size_t)s0 * HIDDEN + c);
  uint2 b0 = *reinterpret_cast<const uint2*>(y  + (size_t)s1 * HIDDEN + c);
  uint2 b1 = *reinterpret_cast<const uint2*>(y1 + (size_t)s1 * HIDDEN + c);
  float4 o;
  o.x = g0 * (bf2f(a0.x & 0xffffu) + bf2f(a1.x & 0xffffu))
      + g1 * (bf2f(b0.x & 0xffffu) + bf2f(b1.x & 0xffffu));
  o.y = g0 * (bf2f(a0.x >> 16) + bf2f(a1.x >> 16))
      + g1 * (bf2f(b0.x >> 16) + bf2f(b1.x >> 16));
  o.z = g0 * (bf2f(a0.y & 0xffffu) + bf2f(a1.y & 0xffffu))
      + g1 * (bf2f(b0.y & 0xffffu) + bf2f(b1.y & 0xffffu));
  o.w = g0 * (bf2f(a0.y >> 16) + bf2f(a1.y >> 16))
      + g1 * (bf2f(b0.y >> 16) + bf2f(b1.y >> 16));
  *reinterpret_cast<float4*>(out + (size_t)t * HIDDEN + c) = o;
}

extern "C" void kernel_launch(void* const* d_in, const int* in_sizes, int n_in,
                              void* d_out, int out_size, void* d_ws, size_t ws_size,
                              hipStream_t stream) {
  const float* x   = (const float*)d_in[0];
  const float* rw  = (const float*)d_in[1];
  const int*   w1  = (const int*)d_in[2];
  const float* w1s = (const float*)d_in[3];
  const int*   w2  = (const int*)d_in[4];
  const float* w2s = (const float*)d_in[5];
  float* out = (float*)d_out;
  char* ws = (char*)d_ws;

  int*   topki = (int*)(ws + OFF_TOPKI);
  float* topkw = (float*)(ws + OFF_TOPKW);
  int*   ctrl  = (int*)(ws + OFF_CTRL);
  int*   tok   = (int*)(ws + OFF_TOK);
  int*   slots = (int*)(ws + OFF_SLOT);
  int*   tilemap = (int*)(ws + OFF_TILE);
  int*   tile256 = (int*)(ws + OFF_T256);
  int*   valid256 = (int*)(ws + OFF_V256);
  unsigned short* xb  = (unsigned short*)(ws + OFF_XB);
  unsigned short* a   = (unsigned short*)(ws + OFF_A);
  unsigned short* w1d = (unsigned short*)(ws + OFF_W1D);
  unsigned short* w2d = (unsigned short*)(ws + OFF_W2D);
  unsigned short* y   = (unsigned short*)(ws + OFF_Y0);  // y1 = y + MAXROWS*HIDDEN

  k_prep<<<29697, 256, 0, stream>>>(x, rw, topki, topkw, w1, w1s, w1d, w2, w2s, w2d, xb);
  k_route2<<<1, 256, 0, stream>>>(topki, ctrl, tok, slots, tilemap, tile256, valid256);
  k_gemm1<<<16 * MAXT256, 512, 0, stream>>>(xb, w1d, ctrl, tile256, valid256, tok, a);
  k_gemm2<<<16 * MAXTILES, 256, 0, stream>>>(a, w2d, ctrl, tilemap, y);
  k_combine<<<TOKENS, 256, 0, stream>>>(y, slots, topkw, out);
}

// Round 3
// 325.724 us; speedup vs baseline: 1.3115x; 1.0841x over previous
//
#include <hip/hip_runtime.h>
#include <hip/hip_bf16.h>

#define HIDDEN 1024
#define INTER 2048
#define NE 8
#define GS 128
#define TOKENS 4096
#define MAXROWS 9216  // 8192 routed rows + 8*128 padding capacity
#define MAXTILES 72   // 128-row tiles
#define MAXT256 40    // 256-row tiles (reserved)

typedef __bf16 bf16x8 __attribute__((ext_vector_type(8)));
typedef float f32x4 __attribute__((ext_vector_type(4)));

// ---- ws layout v3 (bytes) ----
#define OFF_TOPKI 0u               // int[4096][2]
#define OFF_TOPKW 32768u           // float[4096][2]
#define OFF_CTRL  65536u           // int[32]
#define OFF_TOK   66048u           // int[MAXROWS]
#define OFF_SLOT  102912u          // int[TOKENS*2]
#define OFF_TILE  135680u          // int[MAXTILES]
#define OFF_T256  136192u          // int[MAXT256]
#define OFF_V256  136448u          // int[MAXT256]
#define OFF_XB    139776u          // bf16[TOKENS+1][HIDDEN]  (row TOKENS = zeros)
#define OFF_A     8530432u         // bf16[MAXROWS][INTER]
#define OFF_W1D   46279168u        // bf16[NE][4096][HIDDEN]  (dead after gemm1)
#define OFF_W2D   113388032u       // bf16[NE][1024][INTER]   -> 146942464 total
#define OFF_Y0    OFF_W1D          // bf16[MAXROWS][HIDDEN]   (aliases dead w1d)
#define OFF_Y1    (OFF_W1D + 18874368u)

__device__ __forceinline__ unsigned short f2bf(float f) {
  union { float f; unsigned int u; } v; v.f = f;
  unsigned int r = (v.u + 0x7FFFu + ((v.u >> 16) & 1u)) >> 16;
  return (unsigned short)r;
}
__device__ __forceinline__ float bf2f(unsigned int u) {
  union { unsigned int u; float f; } v; v.u = u << 16;
  return v.f;
}
__device__ __forceinline__ unsigned int pack2(unsigned short lo, unsigned short hi) {
  return (unsigned int)lo | ((unsigned int)hi << 16);
}

// async global->LDS, 16B per lane. LDS dest is wave-uniform base + lane*16.
typedef const __attribute__((address_space(1))) unsigned int GAS;
typedef __attribute__((address_space(3))) unsigned int LAS;
__device__ __forceinline__ void gload16(const unsigned short* g, unsigned short* l) {
  __builtin_amdgcn_global_load_lds((GAS*)g, (LAS*)l, 16, 0, 0);
}

// ---- prep v2: router+xconv fused | deq1 x4-ILP | deq2 x4-ILP | zero-row ----
// block ranges: [0,1024) router(+xb conv), [1024,5120) deq1, [5120,7168) deq2,
//               7168 zero-row.  Each dequant thread: 4 independent 16B chunks
//               (block-strided so each instruction is wave-coalesced).
__global__ __launch_bounds__(256) void k_prep(const float* __restrict__ x,
    const float* __restrict__ rw, int* __restrict__ topki, float* __restrict__ topkw,
    const int* __restrict__ w1, const float* __restrict__ w1s,
    unsigned short* __restrict__ w1d,
    const int* __restrict__ w2, const float* __restrict__ w2s,
    unsigned short* __restrict__ w2d, unsigned short* __restrict__ xb) {
  int bid = blockIdx.x, tid = threadIdx.x;
  if (bid == 7168) {
    uint2 z; z.x = 0u; z.y = 0u;
    *reinterpret_cast<uint2*>(xb + (size_t)TOKENS * HIDDEN + tid * 4) = z;
    return;
  }
  if (bid >= 5120) {
    // ---- deq2: 4 chunks x 4 int32, block covers 4096 int32 ----
    size_t base = (size_t)(bid - 5120) * 4096 + tid * 4;
    int4 p[4];
#pragma unroll
    for (int c = 0; c < 4; c++)
      p[c] = *reinterpret_cast<const int4*>(w2 + base + c * 1024);
#pragma unroll
    for (int c = 0; c < 4; c++) {
      size_t i4 = base + c * 1024;
      int r = (int)(i4 >> 10);
      int i = (int)(i4 & 1023);
      float s = w2s[r * 16 + (i >> 6)];
      int pv[4] = { p[c].x, p[c].y, p[c].z, p[c].w };
      uint4 o; unsigned int ov[4];
#pragma unroll
      for (int j = 0; j < 4; j++) {
        float lo = (float)((pv[j] & 15) - 8) * s;
        float hi = (float)(((pv[j] >> 4) & 15) - 8) * s;
        ov[j] = pack2(f2bf(lo), f2bf(hi));
      }
      o.x = ov[0]; o.y = ov[1]; o.z = ov[2]; o.w = ov[3];
      *reinterpret_cast<uint4*>(w2d + 2 * i4) = o;   // out shorts = 2*int32 idx
    }
    return;
  }
  if (bid >= 1024) {
    // ---- deq1: 4 chunks x 4 int32, block covers 4096 int32 ----
    size_t base = (size_t)(bid - 1024) * 4096 + tid * 4;
    int4 p[4];
#pragma unroll
    for (int c = 0; c < 4; c++)
      p[c] = *reinterpret_cast<const int4*>(w1 + base + c * 1024);
#pragma unroll
    for (int c = 0; c < 4; c++) {
      size_t i4 = base + c * 1024;
      int r = (int)(i4 >> 9);
      int i = (int)(i4 & 511);
      float s = w1s[r * 8 + (i >> 6)];
      int pv[4] = { p[c].x, p[c].y, p[c].z, p[c].w };
      uint4 o; unsigned int ov[4];
#pragma unroll
      for (int j = 0; j < 4; j++) {
        float lo = (float)((pv[j] & 15) - 8) * s;
        float hi = (float)(((pv[j] >> 4) & 15) - 8) * s;
        ov[j] = pack2(f2bf(lo), f2bf(hi));
      }
      o.x = ov[0]; o.y = ov[1]; o.z = ov[2]; o.w = ov[3];
      *reinterpret_cast<uint4*>(w1d + 2 * i4) = o;
    }
    return;
  }
  // ---- router + xb conversion (fused; x read once) ----
  int wave = tid >> 6, lane = tid & 63;
  int t = bid * 4 + wave;
  const float* xr = x + (size_t)t * HIDDEN;
  float acc[NE];
#pragma unroll
  for (int e = 0; e < NE; e++) acc[e] = 0.f;
#pragma unroll
  for (int j = 0; j < 4; j++) {
    int col = j * 256 + lane * 4;
    float4 xv = *reinterpret_cast<const float4*>(xr + col);
    // write xb (bf16) while x is in registers
    uint2 o;
    o.x = pack2(f2bf(xv.x), f2bf(xv.y));
    o.y = pack2(f2bf(xv.z), f2bf(xv.w));
    *reinterpret_cast<uint2*>(xb + (size_t)t * HIDDEN + col) = o;
#pragma unroll
    for (int e = 0; e < NE; e++) {
      float4 wv = *reinterpret_cast<const float4*>(rw + e * HIDDEN + col);
      acc[e] += xv.x * wv.x + xv.y * wv.y + xv.z * wv.z + xv.w * wv.w;
    }
  }
#pragma unroll
  for (int e = 0; e < NE; e++) {
    float v = acc[e];
    for (int off = 32; off > 0; off >>= 1) v += __shfl_down(v, off, 64);
    acc[e] = v;
  }
  if (lane == 0) {
    int b0 = 0; float s0 = acc[0];
#pragma unroll
    for (int e = 1; e < NE; e++) if (acc[e] > s0) { s0 = acc[e]; b0 = e; }
    int b1 = -1; float s1 = -3.0e38f;
#pragma unroll
    for (int e = 0; e < NE; e++) if (e != b0 && acc[e] > s1) { s1 = acc[e]; b1 = e; }
    float w0 = 1.f / (1.f + __expf(s1 - s0));
    topki[t * 2] = b0; topki[t * 2 + 1] = b1;
    topkw[t * 2] = w0; topkw[t * 2 + 1] = 1.f - w0;
  }
}

// ------- route2 (1 block): hist + offsets + tilemaps + pad fill + scatter ---
__global__ __launch_bounds__(256) void k_route2(const int* __restrict__ topki,
    int* __restrict__ ctrl, int* __restrict__ tok, int* __restrict__ slots,
    int* __restrict__ tilemap, int* __restrict__ tile256, int* __restrict__ valid256) {
  __shared__ int h[NE], off[NE], cnt[NE];
  int tid = threadIdx.x;
  if (tid < NE) h[tid] = 0;
  __syncthreads();
  for (int i = tid; i < TOKENS * 2; i += 256) atomicAdd(&h[topki[i]], 1);
  __syncthreads();
  if (tid == 0) {
    int run = 0, t = 0, t2 = 0;
    for (int e = 0; e < NE; e++) {
      int c = h[e];
      ctrl[e] = c; ctrl[16 + e] = run; off[e] = run;
      int pc = (c + 127) & ~127;
      int m = pc >> 7;
      for (int mt = 0; mt < m; mt++) tilemap[t++] = (e << 20) | (run + mt * 128);
      int n2 = (m + 1) >> 1;
      for (int i2 = 0; i2 < n2; i2++) {
        int st = i2 * 256;
        if (st + 256 > pc) st = (pc >= 256) ? (pc - 256) : 0;
        tile256[t2] = (e << 20) | (run + st);
        int v = pc - st; valid256[t2] = (v < 256) ? v : 256;
        t2++;
      }
      run += pc;
    }
    ctrl[24] = run; ctrl[25] = t; ctrl[26] = t2;
  }
  __syncthreads();
#pragma unroll
  for (int e = 0; e < NE; e++) {
    int c = h[e], pc = (c + 127) & ~127;
    for (int i = c + tid; i < pc; i += 256) tok[off[e] + i] = -1;
  }
  if (tid < NE) cnt[tid] = off[tid];
  __syncthreads();
  for (int i = tid; i < TOKENS * 2; i += 256) {
    int e = topki[i];
    int p = atomicAdd(&cnt[e], 1);
    tok[p] = i >> 1;
    slots[i] = p;
  }
}

// --------------- GEMM1: h = gather(xb) @ w1^T, silu(gate)*up -> a ----------
// EXACT round-0 version (measured 101 us / 30% MfmaUtil / 0 conflicts).
// 128 rows x (64 gate + 64 up) cols, BK=32, swizzled LDS, async staging.
__global__ __launch_bounds__(256) void k_gemm1(
    const unsigned short* __restrict__ xb, const unsigned short* __restrict__ w1d,
    const int* __restrict__ ctrl, const int* __restrict__ tilemap,
    const int* __restrict__ tok, unsigned short* __restrict__ a_out) {
  __shared__ unsigned short sA[128 * 32];   // 8 KB
  __shared__ unsigned short sBg[64 * 32];   // 4 KB
  __shared__ unsigned short sBu[64 * 32];   // 4 KB
  int bid = blockIdx.x, tid = threadIdx.x;
  int nt = bid & 31, tile = bid >> 5;
  if (tile >= ctrl[25]) return;
  int tm = tilemap[tile];
  int e = tm >> 20, row0 = tm & 0xFFFFF;
  int n0 = nt * 64;
  int wave = tid >> 6, lane = tid & 63;
  int ln = lane & 15, quad = lane >> 4;
  int wr = (wave & 1) * 64, wc = (wave >> 1) * 32;

  int srow = tid >> 2, scblk = tid & 3;
  int scol = (scblk ^ ((srow >> 1) & 3)) * 8;
  int t0 = tok[row0 + srow];
  int t1 = tok[row0 + 64 + srow];
  const unsigned short* gA0 = xb + (size_t)(t0 < 0 ? TOKENS : t0) * HIDDEN + scol;
  const unsigned short* gA1 = xb + (size_t)(t1 < 0 ? TOKENS : t1) * HIDDEN + scol;
  const unsigned short* gBg = w1d + ((size_t)e * 4096 + n0 + srow) * HIDDEN + scol;
  const unsigned short* gBu = gBg + (size_t)INTER * HIDDEN;
  unsigned short* lA0 = sA + tid * 8;
  unsigned short* lA1 = sA + 64 * 32 + tid * 8;
  unsigned short* lBg = sBg + tid * 8;
  unsigned short* lBu = sBu + tid * 8;

  f32x4 aG[4][2] = {}, aU[4][2] = {};
  for (int k0 = 0; k0 < HIDDEN; k0 += 32) {
    __syncthreads();
    gload16(gA0 + k0, lA0);
    gload16(gA1 + k0, lA1);
    gload16(gBg + k0, lBg);
    gload16(gBu + k0, lBu);
    __syncthreads();
    bf16x8 af[4], bg[2], bu[2];
#pragma unroll
    for (int m = 0; m < 4; m++) {
      int ar = wr + m * 16 + ln;
      af[m] = *reinterpret_cast<const bf16x8*>(&sA[ar * 32 + (quad ^ ((ar >> 1) & 3)) * 8]);
    }
#pragma unroll
    for (int n = 0; n < 2; n++) {
      int br = wc + n * 16 + ln;
      int bo = br * 32 + (quad ^ ((br >> 1) & 3)) * 8;
      bg[n] = *reinterpret_cast<const bf16x8*>(&sBg[bo]);
      bu[n] = *reinterpret_cast<const bf16x8*>(&sBu[bo]);
    }
#pragma unroll
    for (int m = 0; m < 4; m++)
#pragma unroll
      for (int n = 0; n < 2; n++) {
        aG[m][n] = __builtin_amdgcn_mfma_f32_16x16x32_bf16(af[m], bg[n], aG[m][n], 0, 0, 0);
        aU[m][n] = __builtin_amdgcn_mfma_f32_16x16x32_bf16(af[m], bu[n], aU[m][n], 0, 0, 0);
      }
  }
#pragma unroll
  for (int m = 0; m < 4; m++)
#pragma unroll
    for (int n = 0; n < 2; n++) {
      int col = n0 + wc + n * 16 + ln;
#pragma unroll
      for (int r = 0; r < 4; r++) {
        float g = aG[m][n][r], u = aU[m][n][r];
        float act = (g / (1.f + __expf(-g))) * u;
        int row = row0 + wr + m * 16 + quad * 4 + r;
        a_out[(size_t)row * INTER + col] = f2bf(act);
      }
    }
}

// ------- GEMM2 split-K x2: y[kp][slot] = a[:,kp*1024:+1024] @ w2^T ---------
// 128x128 tile, BK=32. bid: kp = bid&1, nt = (bid>>1)&7, tile = bid>>4.
__global__ __launch_bounds__(256) void k_gemm2(
    const unsigned short* __restrict__ a_in, const unsigned short* __restrict__ w2d,
    const int* __restrict__ ctrl, const int* __restrict__ tilemap,
    unsigned short* __restrict__ y) {
  __shared__ unsigned short sA[128 * 32];   // 8 KB
  __shared__ unsigned short sB[128 * 32];   // 8 KB
  int bid = blockIdx.x, tid = threadIdx.x;
  int kp = bid & 1, nt = (bid >> 1) & 7, tile = bid >> 4;
  if (tile >= ctrl[25]) return;
  int tm = tilemap[tile];
  int e = tm >> 20, row0 = tm & 0xFFFFF;
  int n0 = nt * 128;
  int wave = tid >> 6, lane = tid & 63;
  int ln = lane & 15, quad = lane >> 4;
  int wr = (wave & 1) * 64, wc = (wave >> 1) * 64;

  int srow = tid >> 2, scblk = tid & 3;
  int scol = (scblk ^ ((srow >> 1) & 3)) * 8;
  int kbase = kp * (INTER / 2);
  const unsigned short* gA0 = a_in + (size_t)(row0 + srow) * INTER + kbase + scol;
  const unsigned short* gA1 = gA0 + (size_t)64 * INTER;
  const unsigned short* gB0 = w2d + ((size_t)e * 1024 + n0 + srow) * INTER + kbase + scol;
  const unsigned short* gB1 = gB0 + (size_t)64 * INTER;
  unsigned short* lA0 = sA + tid * 8;
  unsigned short* lA1 = sA + 64 * 32 + tid * 8;
  unsigned short* lB0 = sB + tid * 8;
  unsigned short* lB1 = sB + 64 * 32 + tid * 8;

  f32x4 acc[4][4] = {};
  for (int k0 = 0; k0 < INTER / 2; k0 += 32) {
    __syncthreads();
    gload16(gA0 + k0, lA0);
    gload16(gA1 + k0, lA1);
    gload16(gB0 + k0, lB0);
    gload16(gB1 + k0, lB1);
    __syncthreads();
    bf16x8 af[4], bf_[4];
#pragma unroll
    for (int m = 0; m < 4; m++) {
      int ar = wr + m * 16 + ln;
      af[m] = *reinterpret_cast<const bf16x8*>(&sA[ar * 32 + (quad ^ ((ar >> 1) & 3)) * 8]);
    }
#pragma unroll
    for (int n = 0; n < 4; n++) {
      int br = wc + n * 16 + ln;
      bf_[n] = *reinterpret_cast<const bf16x8*>(&sB[br * 32 + (quad ^ ((br >> 1) & 3)) * 8]);
    }
#pragma unroll
    for (int m = 0; m < 4; m++)
#pragma unroll
      for (int n = 0; n < 4; n++)
        acc[m][n] = __builtin_amdgcn_mfma_f32_16x16x32_bf16(af[m], bf_[n], acc[m][n], 0, 0, 0);
  }
  unsigned short* yk = y + (size_t)kp * MAXROWS * HIDDEN;
#pragma unroll
  for (int m = 0; m < 4; m++)
#pragma unroll
    for (int n = 0; n < 4; n++) {
      int col = n0 + wc + n * 16 + ln;
#pragma unroll
      for (int r = 0; r < 4; r++) {
        int row = row0 + wr + m * 16 + quad * 4 + r;
        yk[(size_t)row * HIDDEN + col] = f2bf(acc[m][n][r]);
      }
    }
}

// ------- combine: out[t] = g0*(y0[s0]+y1[s0]) + g1*(y0[s1]+y1[s1]) ---------
__global__ __launch_bounds__(256) void k_combine(const unsigned short* __restrict__ y,
    const int* __restrict__ slots, const float* __restrict__ topkw,
    float* __restrict__ out) {
  int t = blockIdx.x;
  int c = threadIdx.x * 4;
  int s0 = slots[t * 2], s1 = slots[t * 2 + 1];
  float g0 = topkw[t * 2], g1 = topkw[t * 2 + 1];
  const unsigned short* y1 = y + (size_t)MAXROWS * HIDDEN;
  uint2 a0 = *reinterpret_cast<const uint2*>(y  + (size_t)s0 * HIDDEN + c);
  uint2 a1 = *reinterpret_cast<const uint2*>(y1 + (size_t)s0 * HIDDEN + c);
  uint2 b0 = *reinterpret_cast<const uint2*>(y  + (size_t)s1 * HIDDEN + c);
  uint2 b1 = *reinterpret_cast<const uint2*>(y1 + (size_t)s1 * HIDDEN + c);
  float4 o;
  o.x = g0 * (bf2f(a0.x & 0xffffu) + bf2f(a1.x & 0xffffu))
      + g1 * (bf2f(b0.x & 0xffffu) + bf2f(b1.x & 0xffffu));
  o.y = g0 * (bf2f(a0.x >> 16) + bf2f(a1.x >> 16))
      + g1 * (bf2f(b0.x >> 16) + bf2f(b1.x >> 16));
  o.z = g0 * (bf2f(a0.y & 0xffffu) + bf2f(a1.y & 0xffffu))
      + g1 * (bf2f(b0.y & 0xffffu) + bf2f(b1.y & 0xffffu));
  o.w = g0 * (bf2f(a0.y >> 16) + bf2f(a1.y >> 16))
      + g1 * (bf2f(b0.y >> 16) + bf2f(b1.y >> 16));
  *reinterpret_cast<float4*>(out + (size_t)t * HIDDEN + c) = o;
}

extern "C" void kernel_launch(void* const* d_in, const int* in_sizes, int n_in,
                              void* d_out, int out_size, void* d_ws, size_t ws_size,
                              hipStream_t stream) {
  const float* x   = (const float*)d_in[0];
  const float* rw  = (const float*)d_in[1];
  const int*   w1  = (const int*)d_in[2];
  const float* w1s = (const float*)d_in[3];
  const int*   w2  = (const int*)d_in[4];
  const float* w2s = (const float*)d_in[5];
  float* out = (float*)d_out;
  char* ws = (char*)d_ws;

  int*   topki = (int*)(ws + OFF_TOPKI);
  float* topkw = (float*)(ws + OFF_TOPKW);
  int*   ctrl  = (int*)(ws + OFF_CTRL);
  int*   tok   = (int*)(ws + OFF_TOK);
  int*   slots = (int*)(ws + OFF_SLOT);
  int*   tilemap = (int*)(ws + OFF_TILE);
  int*   tile256 = (int*)(ws + OFF_T256);
  int*   valid256 = (int*)(ws + OFF_V256);
  unsigned short* xb  = (unsigned short*)(ws + OFF_XB);
  unsigned short* a   = (unsigned short*)(ws + OFF_A);
  unsigned short* w1d = (unsigned short*)(ws + OFF_W1D);
  unsigned short* w2d = (unsigned short*)(ws + OFF_W2D);
  unsigned short* y   = (unsigned short*)(ws + OFF_Y0);  // y1 = y + MAXROWS*HIDDEN

  k_prep<<<7169, 256, 0, stream>>>(x, rw, topki, topkw, w1, w1s, w1d, w2, w2s, w2d, xb);
  k_route2<<<1, 256, 0, stream>>>(topki, ctrl, tok, slots, tilemap, tile256, valid256);
  k_gemm1<<<32 * MAXTILES, 256, 0, stream>>>(xb, w1d, ctrl, tilemap, tok, a);
  k_gemm2<<<16 * MAXTILES, 256, 0, stream>>>(a, w2d, ctrl, tilemap, y);
  k_combine<<<TOKENS, 256, 0, stream>>>(y, slots, topkw, out);
}